// Round 4
// baseline (794.465 us; speedup 1.0000x reference)
//
#include <hip/hip_runtime.h>
#include <math.h>

#define N_NODES 200000
#define BGRAPH  1024
#define HDIM    256
#define ODIM    128
#define SCAP    1024   // max segment length cached in LDS (actual max ~250)

__device__ __forceinline__ unsigned short f2bf(float f) {
    union { float f; unsigned int i; } c; c.f = f;
    unsigned int i = c.i;
    unsigned int r = i + 0x7FFFu + ((i >> 16) & 1u);  // RNE
    return (unsigned short)(r >> 16);
}
// bf16 pair decode: low half costs 1 shift, high half costs 1 AND
__device__ __forceinline__ float bflo(unsigned int u) {
    union { unsigned int i; float f; } c; c.i = u << 16; return c.f;
}
__device__ __forceinline__ float bfhi(unsigned int u) {
    union { unsigned int i; float f; } c; c.i = u & 0xffff0000u; return c.f;
}

// ---------------------------------------------------------------------------
// k_prep:
//   blocks 0..255   : v[i] = W[i,:].att_src, u[i] = W[i,:].att_dst
//   blocks 256..260 : segment bounds via binary search (batch sorted)
//   blocks 261..516 : pack GRU weights 6 x bf16 = 12B per (k,t):
//                     [Wih_r, Wih_z, Wih_n, Whh_r, Whh_z, Whh_n][k][t]
//   blocks 517..644 : pack W as bf16 pairs: Wpk[k2][t] = (W[2k2][t], W[2k2+1][t])
__global__ __launch_bounds__(256) void k_prep(const float* __restrict__ W,
        const float* __restrict__ att_src, const float* __restrict__ att_dst,
        const int* __restrict__ batch, const float* __restrict__ W_ih,
        const float* __restrict__ W_hh, float* __restrict__ v,
        float* __restrict__ u, int* __restrict__ seg,
        unsigned int* __restrict__ Wgu, unsigned int* __restrict__ Wpk) {
    int t = threadIdx.x;
    if (blockIdx.x < 256) {
        int i = blockIdx.x;
        float w = W[(size_t)i * HDIM + t];
        __shared__ float r1[256], r2[256];
        r1[t] = w * att_src[t];
        r2[t] = w * att_dst[t];
        __syncthreads();
        for (int st = 128; st > 0; st >>= 1) {
            if (t < st) { r1[t] += r1[t + st]; r2[t] += r2[t + st]; }
            __syncthreads();
        }
        if (t == 0) { v[i] = r1[0]; u[i] = r2[0]; }
    } else if (blockIdx.x < 261) {
        int b = (blockIdx.x - 256) * 256 + t;
        if (b > BGRAPH) return;
        if (b == BGRAPH) { seg[b] = N_NODES; return; }
        int lo = 0, hi = N_NODES;
        while (lo < hi) { int mid = (lo + hi) >> 1; if (batch[mid] < b) lo = mid + 1; else hi = mid; }
        seg[b] = lo;
    } else if (blockIdx.x < 517) {
        int k = blockIdx.x - 261;            // 0..255
        unsigned int a0 = f2bf(W_ih[(size_t)(0 * HDIM + t) * HDIM + k]);
        unsigned int a1 = f2bf(W_ih[(size_t)(1 * HDIM + t) * HDIM + k]);
        unsigned int a2 = f2bf(W_ih[(size_t)(2 * HDIM + t) * HDIM + k]);
        unsigned int a3 = f2bf(W_hh[(size_t)(0 * HDIM + t) * HDIM + k]);
        unsigned int a4 = f2bf(W_hh[(size_t)(1 * HDIM + t) * HDIM + k]);
        unsigned int a5 = f2bf(W_hh[(size_t)(2 * HDIM + t) * HDIM + k]);
        unsigned int* p = Wgu + ((size_t)k * HDIM + t) * 3;
        p[0] = a0 | (a1 << 16);
        p[1] = a2 | (a3 << 16);
        p[2] = a4 | (a5 << 16);
    } else {
        int k2 = blockIdx.x - 517;           // 0..127
        unsigned int lo16 = f2bf(W[(size_t)(2 * k2) * HDIM + t]);
        unsigned int hi16 = f2bf(W[(size_t)(2 * k2 + 1) * HDIM + t]);
        Wpk[(size_t)k2 * HDIM + t] = lo16 | (hi16 << 16);
    }
}

// ---------------------------------------------------------------------------
// k_fused: one graph per 512-thread block (8 waves). grid 1024 -> 4
// INDEPENDENT blocks/CU x 8 waves = 32 waves/CU (100% of slots), doubling
// occupancy vs the 256-thread version while keeping cross-block phase overlap
// (R3 showed the 1024-thread lockstep variant loses ~10us). Narrow phases use
// 2-way k-splits (h-matvec, GRU) and 4-way (final) so all 8 waves contribute.
__global__ __launch_bounds__(512, 8) void k_fused(const float* __restrict__ x,
        const int* __restrict__ seg, const float* __restrict__ v,
        const float* __restrict__ u, const float* __restrict__ bias_gat,
        const unsigned int* __restrict__ Wgu, const unsigned int* __restrict__ Wpk,
        const float* __restrict__ b_ih, const float* __restrict__ b_hh,
        const float* __restrict__ W_lin, const float* __restrict__ b_lin,
        float* __restrict__ sfall, float* __restrict__ out) {
    int b = blockIdx.x;
    int lo = seg[b], hi = seg[b + 1];
    int t = threadIdx.x, wv = t >> 6, lane = t & 63;

    __shared__ float s_loc[SCAP];      // per-row scores, persists all phases
    __shared__ float comb[8][HDIM];    // cross-wave reduce scratch (reused)
    __shared__ float red[HDIM];        // scalar reduce scratch
    __shared__ float axv[HDIM];        // weighted-average vector
    __shared__ float hvec[HDIM];       // GAT output h (GRU input)
    __shared__ float oprev[HDIM];      // running out (pool -> out1 -> out2)
    __shared__ float sred[8], dred[8];

    bool inl = (hi - lo) <= SCAP;
    float ut = u[t & 255];

    // ================= pass 1: pool + s + smax (HBM sweep) =================
    float v0 = v[4 * lane + 0], v1 = v[4 * lane + 1];
    float v2 = v[4 * lane + 2], v3 = v[4 * lane + 3];
    float p0 = 0.f, p1 = 0.f, p2 = 0.f, p3 = 0.f;
    float sm = -3.402823466e38f;
    int i = lo + wv;
    for (; i + 8 < hi; i += 16) {
        const float4 r0 = *(const float4*)(x + (size_t)i * HDIM + 4 * lane);
        const float4 r1 = *(const float4*)(x + (size_t)(i + 8) * HDIM + 4 * lane);
        p0 += r0.x + r1.x; p1 += r0.y + r1.y; p2 += r0.z + r1.z; p3 += r0.w + r1.w;
        float pa = r0.x * v0 + r0.y * v1 + r0.z * v2 + r0.w * v3;
        float pb = r1.x * v0 + r1.y * v1 + r1.z * v2 + r1.w * v3;
        #pragma unroll
        for (int off = 32; off > 0; off >>= 1) {
            pa += __shfl_down(pa, off, 64);
            pb += __shfl_down(pb, off, 64);
        }
        if (lane == 0) {
            if (inl) { s_loc[i - lo] = pa; s_loc[i + 8 - lo] = pb; }
            else     { sfall[i] = pa; sfall[i + 8] = pb; }
            sm = fmaxf(sm, fmaxf(pa, pb));
        }
    }
    for (; i < hi; i += 8) {
        const float4 r0 = *(const float4*)(x + (size_t)i * HDIM + 4 * lane);
        p0 += r0.x; p1 += r0.y; p2 += r0.z; p3 += r0.w;
        float pa = r0.x * v0 + r0.y * v1 + r0.z * v2 + r0.w * v3;
        #pragma unroll
        for (int off = 32; off > 0; off >>= 1) pa += __shfl_down(pa, off, 64);
        if (lane == 0) {
            if (inl) s_loc[i - lo] = pa; else sfall[i] = pa;
            sm = fmaxf(sm, pa);
        }
    }
    comb[wv][4 * lane + 0] = p0; comb[wv][4 * lane + 1] = p1;
    comb[wv][4 * lane + 2] = p2; comb[wv][4 * lane + 3] = p3;
    if (lane == 0) sred[wv] = sm;
    __syncthreads();
    if (t < HDIM) {
        float st0 = 0.f;
        #pragma unroll
        for (int j = 0; j < 8; ++j) st0 += comb[j][t];
        oprev[t] = st0;                              // out0 = pooled sum
        red[t] = st0 * ut;
    }
    float smx = fmaxf(fmaxf(fmaxf(sred[0], sred[1]), fmaxf(sred[2], sred[3])),
                      fmaxf(fmaxf(sred[4], sred[5]), fmaxf(sred[6], sred[7])));
    __syncthreads();
    for (int st = 128; st > 0; st >>= 1) { if (t < st) red[t] += red[t + st]; __syncthreads(); }
    float d = red[0];                                // d1 = out0 . u
    __syncthreads();

    int q = t >> 8, tt = t & 255;                    // 2-way k-split roles

    // ================= T = 2 recurrence, all block-local =================
    for (int step = 0; step < 2; ++step) {
        float M = smx + d;
        M = M > 0.f ? M : 0.01f * M;                 // max of leakyrelu(s_i+d)

        // ---- weighted aggregation sweep (x L3-hot after pass 1), 8 waves ----
        float a0 = 0.f, a1 = 0.f, a2 = 0.f, a3 = 0.f, den = 0.f;
        i = lo + wv;
        for (; i + 24 < hi; i += 32) {
            float s0v = inl ? s_loc[i - lo]      : sfall[i];
            float s1v = inl ? s_loc[i + 8 - lo]  : sfall[i + 8];
            float s2v = inl ? s_loc[i + 16 - lo] : sfall[i + 16];
            float s3v = inl ? s_loc[i + 24 - lo] : sfall[i + 24];
            float e0 = s0v + d; e0 = e0 > 0.f ? e0 : 0.01f * e0;
            float e1 = s1v + d; e1 = e1 > 0.f ? e1 : 0.01f * e1;
            float e2 = s2v + d; e2 = e2 > 0.f ? e2 : 0.01f * e2;
            float e3 = s3v + d; e3 = e3 > 0.f ? e3 : 0.01f * e3;
            float w0 = __expf(e0 - M), w1 = __expf(e1 - M);
            float w2 = __expf(e2 - M), w3 = __expf(e3 - M);
            const float4 r0 = *(const float4*)(x + (size_t)i * HDIM + 4 * lane);
            const float4 r1 = *(const float4*)(x + (size_t)(i + 8) * HDIM + 4 * lane);
            const float4 r2 = *(const float4*)(x + (size_t)(i + 16) * HDIM + 4 * lane);
            const float4 r3 = *(const float4*)(x + (size_t)(i + 24) * HDIM + 4 * lane);
            den += (w0 + w1) + (w2 + w3);
            a0 += w0 * r0.x + w1 * r1.x + w2 * r2.x + w3 * r3.x;
            a1 += w0 * r0.y + w1 * r1.y + w2 * r2.y + w3 * r3.y;
            a2 += w0 * r0.z + w1 * r1.z + w2 * r2.z + w3 * r3.z;
            a3 += w0 * r0.w + w1 * r1.w + w2 * r2.w + w3 * r3.w;
        }
        for (; i < hi; i += 8) {
            float s0v = inl ? s_loc[i - lo] : sfall[i];
            float e0 = s0v + d; e0 = e0 > 0.f ? e0 : 0.01f * e0;
            float w0 = __expf(e0 - M);
            const float4 r0 = *(const float4*)(x + (size_t)i * HDIM + 4 * lane);
            den += w0;
            a0 += w0 * r0.x; a1 += w0 * r0.y; a2 += w0 * r0.z; a3 += w0 * r0.w;
        }
        comb[wv][4 * lane + 0] = a0; comb[wv][4 * lane + 1] = a1;
        comb[wv][4 * lane + 2] = a2; comb[wv][4 * lane + 3] = a3;
        if (lane == 0) dred[wv] = den;
        __syncthreads();
        float dtot = (dred[0] + dred[1]) + (dred[2] + dred[3])
                   + (dred[4] + dred[5]) + (dred[6] + dred[7]);
        float inv = (hi > lo) ? 1.0f / dtot : 0.f;
        if (t < HDIM) {
            float s8 = 0.f;
            #pragma unroll
            for (int j = 0; j < 8; ++j) s8 += comb[j][t];
            axv[t] = s8 * inv;
        }
        __syncthreads();

        // ---- h = elu(ax @ W + bias), bf16-pair W, 2-way k-split ----
        {
            float acc = q ? 0.f : bias_gat[tt];
            int k2e = q * 64 + 64;
            for (int k2 = q * 64; k2 < k2e; ++k2) {
                unsigned int w2 = Wpk[(size_t)k2 * HDIM + tt];
                float2 a2 = *(const float2*)&axv[2 * k2];
                acc += a2.x * bflo(w2) + a2.y * bfhi(w2);
            }
            comb[q][tt] = acc;
        }
        __syncthreads();
        if (t < HDIM) {
            float hs = comb[0][t] + comb[1][t];
            hvec[t] = hs > 0.f ? hs : expm1f(hs);
        }
        __syncthreads();

        // ---- GRU matvecs, 2-way k-split over packed 6xbf16 weights ----
        float gr = 0.f, gz = 0.f, gn = 0.f, hr = 0.f, hz = 0.f, hn = 0.f;
        {
            int k0e = q * 128 + 128;
            for (int k0 = q * 128; k0 < k0e; k0 += 4) {
                float hq[4], oq[4];
                *(float4*)hq = *(const float4*)&hvec[k0];
                *(float4*)oq = *(const float4*)&oprev[k0];
                #pragma unroll
                for (int j = 0; j < 4; ++j) {
                    const unsigned int* p = Wgu + ((size_t)(k0 + j) * HDIM + tt) * 3;
                    unsigned int u0 = p[0], u1 = p[1], u2 = p[2];
                    gr += hq[j] * bflo(u0);
                    gz += hq[j] * bfhi(u0);
                    gn += hq[j] * bflo(u1);
                    hr += oq[j] * bfhi(u1);
                    hz += oq[j] * bflo(u2);
                    hn += oq[j] * bfhi(u2);
                }
            }
        }
        if (q == 1) {
            comb[0][tt] = gr; comb[1][tt] = gz; comb[2][tt] = gn;
            comb[3][tt] = hr; comb[4][tt] = hz; comb[5][tt] = hn;
        }
        __syncthreads();
        if (q == 0) {
            float gir = gr + comb[0][tt] + b_ih[tt];
            float giz = gz + comb[1][tt] + b_ih[HDIM + tt];
            float gin = gn + comb[2][tt] + b_ih[2 * HDIM + tt];
            float ghr = hr + comb[3][tt] + b_hh[tt];
            float ghz = hz + comb[4][tt] + b_hh[HDIM + tt];
            float ghn = hn + comb[5][tt] + b_hh[2 * HDIM + tt];
            float rg = 1.f / (1.f + __expf(-(gir + ghr)));
            float zg = 1.f / (1.f + __expf(-(giz + ghz)));
            float ng = tanhf(gin + rg * ghn);
            float prev = oprev[tt];
            float h2 = (1.f - zg) * ng + zg * prev;
            float no = h2 / (1.f + __expf(-h2));      // silu
            oprev[tt] = no;                           // all reads done pre-barrier
            red[tt] = no * ut;
        }
        __syncthreads();
        for (int st = 128; st > 0; st >>= 1) { if (t < st) red[t] += red[t + st]; __syncthreads(); }
        d = red[0];                                   // d for next timestep
        __syncthreads();
    }

    // ============ final: out2 @ W_lin + b_lin (fp32, 4-way k-split) ============
    {
        int qq = t >> 7, o = t & 127;                 // qq in [0,4)
        float acc = 0.f;
        int ke = qq * 64 + 64;
        #pragma unroll 8
        for (int k = qq * 64; k < ke; ++k)
            acc += oprev[k] * W_lin[(size_t)k * ODIM + o];
        comb[qq][o] = acc;
    }
    __syncthreads();
    if (t < ODIM)
        out[(size_t)b * ODIM + t] = (comb[0][t] + comb[1][t])
                                  + (comb[2][t] + comb[3][t]) + b_lin[t];
}

extern "C" void kernel_launch(void* const* d_in, const int* in_sizes, int n_in,
                              void* d_out, int out_size, void* d_ws, size_t ws_size,
                              hipStream_t stream) {
    const float* x        = (const float*)d_in[0];
    const int*   batch    = (const int*)d_in[1];
    const float* W        = (const float*)d_in[2];
    const float* att_src  = (const float*)d_in[3];
    const float* att_dst  = (const float*)d_in[4];
    const float* bias_gat = (const float*)d_in[5];
    const float* W_ih     = (const float*)d_in[6];
    const float* W_hh     = (const float*)d_in[7];
    const float* b_ih     = (const float*)d_in[8];
    const float* b_hh     = (const float*)d_in[9];
    const float* W_lin    = (const float*)d_in[10];
    const float* b_lin    = (const float*)d_in[11];

    char* ws = (char*)d_ws;
    size_t off = 0;
    auto alloc = [&](size_t bytes) {
        void* p = (void*)(ws + off);
        off += (bytes + 255) & ~(size_t)255;
        return p;
    };
    int*          seg   = (int*)alloc((BGRAPH + 1) * 4);
    float*        vv    = (float*)alloc(HDIM * 4);
    float*        uu    = (float*)alloc(HDIM * 4);
    float*        sfall = (float*)alloc((size_t)N_NODES * 4);
    unsigned int* Wgu   = (unsigned int*)alloc((size_t)HDIM * HDIM * 3 * 4);
    unsigned int* Wpk   = (unsigned int*)alloc((size_t)(HDIM / 2) * HDIM * 4);

    hipLaunchKernelGGL(k_prep, dim3(645), dim3(256), 0, stream,
                       W, att_src, att_dst, batch, W_ih, W_hh, vv, uu, seg, Wgu, Wpk);
    hipLaunchKernelGGL(k_fused, dim3(BGRAPH), dim3(512), 0, stream,
                       x, seg, vv, uu, bias_gat, Wgu, Wpk, b_ih, b_hh,
                       W_lin, b_lin, sfall, (float*)d_out);
}

// Round 6
// 575.971 us; speedup vs baseline: 1.3793x; 1.3793x over previous
//
#include <hip/hip_runtime.h>
#include <math.h>

#define N_NODES 200000
#define BGRAPH  1024
#define HDIM    256
#define ODIM    128
#define CROWS   128    // x rows cached per graph in LDS (bf16)
#define SLEN    512    // max segment length with scores in LDS (actual max ~250)

__device__ __forceinline__ unsigned short f2bf(float f) {
    union { float f; unsigned int i; } c; c.f = f;
    unsigned int i = c.i;
    unsigned int r = i + 0x7FFFu + ((i >> 16) & 1u);  // RNE
    return (unsigned short)(r >> 16);
}
// bf16 pair decode: low half = <<16, high half = AND mask
__device__ __forceinline__ float bflo(unsigned int u) {
    union { unsigned int i; float f; } c; c.i = u << 16; return c.f;
}
__device__ __forceinline__ float bfhi(unsigned int u) {
    union { unsigned int i; float f; } c; c.i = u & 0xffff0000u; return c.f;
}

// ---------------------------------------------------------------------------
// k_prep:
//   blocks 0..255   : v[i] = W[i,:].att_src, u[i] = W[i,:].att_dst
//   blocks 256..260 : segment bounds via binary search (batch sorted)
//   blocks 261..516 : pack GRU weights into 3 coalesced bf16-pair planes:
//                     G0[k*256+t]=Wih_r|Wih_z  G1=Wih_n|Whh_r  G2=Whh_z|Whh_n
//   blocks 517..644 : pack W as bf16 pairs: Wpk[k2*256+t]=(W[2k2][t],W[2k2+1][t])
__global__ __launch_bounds__(256) void k_prep(const float* __restrict__ W,
        const float* __restrict__ att_src, const float* __restrict__ att_dst,
        const int* __restrict__ batch, const float* __restrict__ W_ih,
        const float* __restrict__ W_hh, float* __restrict__ v,
        float* __restrict__ u, int* __restrict__ seg,
        unsigned int* __restrict__ Wgu, unsigned int* __restrict__ Wpk) {
    int t = threadIdx.x;
    if (blockIdx.x < 256) {
        int i = blockIdx.x;
        float w = W[(size_t)i * HDIM + t];
        __shared__ float r1[256], r2[256];
        r1[t] = w * att_src[t];
        r2[t] = w * att_dst[t];
        __syncthreads();
        for (int st = 128; st > 0; st >>= 1) {
            if (t < st) { r1[t] += r1[t + st]; r2[t] += r2[t + st]; }
            __syncthreads();
        }
        if (t == 0) { v[i] = r1[0]; u[i] = r2[0]; }
    } else if (blockIdx.x < 261) {
        int b = (blockIdx.x - 256) * 256 + t;
        if (b > BGRAPH) return;
        if (b == BGRAPH) { seg[b] = N_NODES; return; }
        int lo = 0, hi = N_NODES;
        while (lo < hi) { int mid = (lo + hi) >> 1; if (batch[mid] < b) lo = mid + 1; else hi = mid; }
        seg[b] = lo;
    } else if (blockIdx.x < 517) {
        int k = blockIdx.x - 261;            // 0..255
        unsigned int a0 = f2bf(W_ih[(size_t)(0 * HDIM + t) * HDIM + k]);
        unsigned int a1 = f2bf(W_ih[(size_t)(1 * HDIM + t) * HDIM + k]);
        unsigned int a2 = f2bf(W_ih[(size_t)(2 * HDIM + t) * HDIM + k]);
        unsigned int a3 = f2bf(W_hh[(size_t)(0 * HDIM + t) * HDIM + k]);
        unsigned int a4 = f2bf(W_hh[(size_t)(1 * HDIM + t) * HDIM + k]);
        unsigned int a5 = f2bf(W_hh[(size_t)(2 * HDIM + t) * HDIM + k]);
        int kt = k * HDIM + t;
        Wgu[kt]                   = a0 | (a1 << 16);
        Wgu[HDIM * HDIM + kt]     = a2 | (a3 << 16);
        Wgu[2 * HDIM * HDIM + kt] = a4 | (a5 << 16);
    } else {
        int k2 = blockIdx.x - 517;           // 0..127
        unsigned int lo16 = f2bf(W[(size_t)(2 * k2) * HDIM + t]);
        unsigned int hi16 = f2bf(W[(size_t)(2 * k2 + 1) * HDIM + t]);
        Wpk[(size_t)k2 * HDIM + t] = lo16 | (hi16 << 16);
    }
}

// ---------------------------------------------------------------------------
// k_fused: one graph per 512-thread block (8 waves), grid 1024.
// Pass 1 streams x from HBM and CACHES the first CROWS=128 rows in LDS as
// bf16 (64 KB) -> both aggregation sweeps read mostly LDS instead of L3.
// LDS ~78 KB -> 2 independent blocks/CU (16 waves) for phase overlap.
// __launch_bounds__(512,4): 128-VGPR cap, no spills (R4's (512,8) spilled:
// VGPR 32, 648 MB scratch writes).
__global__ __launch_bounds__(512, 4) void k_fused(const float* __restrict__ x,
        const int* __restrict__ seg, const float* __restrict__ v,
        const float* __restrict__ u, const float* __restrict__ bias_gat,
        const unsigned int* __restrict__ Wgu, const unsigned int* __restrict__ Wpk,
        const float* __restrict__ b_ih, const float* __restrict__ b_hh,
        const float* __restrict__ W_lin, const float* __restrict__ b_lin,
        float* __restrict__ sfall, float* __restrict__ out) {
    int b = blockIdx.x;
    int lo = seg[b], hi = seg[b + 1];
    int len = hi - lo;
    int t = threadIdx.x, wv = t >> 6, lane = t & 63;

    __shared__ unsigned int xc2[CROWS][HDIM / 2];  // 64 KB bf16 row cache
    __shared__ float s_loc[SLEN];      // per-row scores
    __shared__ float comb[8][HDIM];    // cross-wave reduce scratch (reused)
    __shared__ float red[HDIM];        // scalar reduce scratch
    __shared__ float axv[HDIM];        // weighted-average vector
    __shared__ float hvec[HDIM];       // GAT output h (GRU input)
    __shared__ float oprev[HDIM];      // running out (pool -> out1 -> out2)
    __shared__ float sred[8], dred[8];

    bool inl = len <= SLEN;
    int clen = len < CROWS ? len : CROWS;
    float ut = u[t & 255];

    // ================= pass 1: pool + s + smax + bf16 cache =================
    float v0 = v[4 * lane + 0], v1 = v[4 * lane + 1];
    float v2 = v[4 * lane + 2], v3 = v[4 * lane + 3];
    float p0 = 0.f, p1 = 0.f, p2 = 0.f, p3 = 0.f;
    float sm = -3.402823466e38f;
    int i = lo + wv;
    for (; i + 8 < hi; i += 16) {
        const float4 r0 = *(const float4*)(x + (size_t)i * HDIM + 4 * lane);
        const float4 r1 = *(const float4*)(x + (size_t)(i + 8) * HDIM + 4 * lane);
        p0 += r0.x + r1.x; p1 += r0.y + r1.y; p2 += r0.z + r1.z; p3 += r0.w + r1.w;
        float pa = r0.x * v0 + r0.y * v1 + r0.z * v2 + r0.w * v3;
        float pb = r1.x * v0 + r1.y * v1 + r1.z * v2 + r1.w * v3;
        #pragma unroll
        for (int off = 32; off > 0; off >>= 1) {
            pa += __shfl_down(pa, off, 64);
            pb += __shfl_down(pb, off, 64);
        }
        int ra = i - lo, rb = ra + 8;
        if (ra < CROWS) {   // wave-uniform branch
            unsigned int c0 = (__float_as_uint(r0.y) & 0xffff0000u) | (__float_as_uint(r0.x) >> 16);
            unsigned int c1 = (__float_as_uint(r0.w) & 0xffff0000u) | (__float_as_uint(r0.z) >> 16);
            *(uint2*)&xc2[ra][2 * lane] = make_uint2(c0, c1);
        }
        if (rb < CROWS) {
            unsigned int c0 = (__float_as_uint(r1.y) & 0xffff0000u) | (__float_as_uint(r1.x) >> 16);
            unsigned int c1 = (__float_as_uint(r1.w) & 0xffff0000u) | (__float_as_uint(r1.z) >> 16);
            *(uint2*)&xc2[rb][2 * lane] = make_uint2(c0, c1);
        }
        if (lane == 0) {
            if (inl) { s_loc[ra] = pa; s_loc[rb] = pb; }
            else     { sfall[i] = pa; sfall[i + 8] = pb; }
            sm = fmaxf(sm, fmaxf(pa, pb));
        }
    }
    for (; i < hi; i += 8) {
        const float4 r0 = *(const float4*)(x + (size_t)i * HDIM + 4 * lane);
        p0 += r0.x; p1 += r0.y; p2 += r0.z; p3 += r0.w;
        float pa = r0.x * v0 + r0.y * v1 + r0.z * v2 + r0.w * v3;
        #pragma unroll
        for (int off = 32; off > 0; off >>= 1) pa += __shfl_down(pa, off, 64);
        int ra = i - lo;
        if (ra < CROWS) {
            unsigned int c0 = (__float_as_uint(r0.y) & 0xffff0000u) | (__float_as_uint(r0.x) >> 16);
            unsigned int c1 = (__float_as_uint(r0.w) & 0xffff0000u) | (__float_as_uint(r0.z) >> 16);
            *(uint2*)&xc2[ra][2 * lane] = make_uint2(c0, c1);
        }
        if (lane == 0) {
            if (inl) s_loc[ra] = pa; else sfall[i] = pa;
            sm = fmaxf(sm, pa);
        }
    }
    comb[wv][4 * lane + 0] = p0; comb[wv][4 * lane + 1] = p1;
    comb[wv][4 * lane + 2] = p2; comb[wv][4 * lane + 3] = p3;
    if (lane == 0) sred[wv] = sm;
    __syncthreads();
    if (t < HDIM) {
        float st0 = 0.f;
        #pragma unroll
        for (int j = 0; j < 8; ++j) st0 += comb[j][t];
        oprev[t] = st0;                              // out0 = pooled sum
        red[t] = st0 * ut;
    }
    float smx = fmaxf(fmaxf(fmaxf(sred[0], sred[1]), fmaxf(sred[2], sred[3])),
                      fmaxf(fmaxf(sred[4], sred[5]), fmaxf(sred[6], sred[7])));
    __syncthreads();
    for (int st = 128; st > 0; st >>= 1) { if (t < st) red[t] += red[t + st]; __syncthreads(); }
    float d = red[0];                                // d1 = out0 . u
    __syncthreads();

    int q = t >> 8, tt = t & 255;                    // 2-way k-split roles

    // ================= T = 2 recurrence, all block-local =================
    for (int step = 0; step < 2; ++step) {
        float M = smx + d;
        M = M > 0.f ? M : 0.01f * M;                 // max of leakyrelu(s_i+d)

        // ---- weighted aggregation: cached rows from LDS (bf16) ----
        float a0 = 0.f, a1 = 0.f, a2 = 0.f, a3 = 0.f, den = 0.f;
        int r = wv;
        for (; r + 24 < clen; r += 32) {
            float s0v = inl ? s_loc[r]      : sfall[lo + r];
            float s1v = inl ? s_loc[r + 8]  : sfall[lo + r + 8];
            float s2v = inl ? s_loc[r + 16] : sfall[lo + r + 16];
            float s3v = inl ? s_loc[r + 24] : sfall[lo + r + 24];
            float e0 = s0v + d; e0 = e0 > 0.f ? e0 : 0.01f * e0;
            float e1 = s1v + d; e1 = e1 > 0.f ? e1 : 0.01f * e1;
            float e2 = s2v + d; e2 = e2 > 0.f ? e2 : 0.01f * e2;
            float e3 = s3v + d; e3 = e3 > 0.f ? e3 : 0.01f * e3;
            float w0 = __expf(e0 - M), w1 = __expf(e1 - M);
            float w2 = __expf(e2 - M), w3 = __expf(e3 - M);
            uint2 q0 = *(const uint2*)&xc2[r][2 * lane];
            uint2 q1 = *(const uint2*)&xc2[r + 8][2 * lane];
            uint2 q2 = *(const uint2*)&xc2[r + 16][2 * lane];
            uint2 q3 = *(const uint2*)&xc2[r + 24][2 * lane];
            den += (w0 + w1) + (w2 + w3);
            a0 += w0 * bflo(q0.x) + w1 * bflo(q1.x) + w2 * bflo(q2.x) + w3 * bflo(q3.x);
            a1 += w0 * bfhi(q0.x) + w1 * bfhi(q1.x) + w2 * bfhi(q2.x) + w3 * bfhi(q3.x);
            a2 += w0 * bflo(q0.y) + w1 * bflo(q1.y) + w2 * bflo(q2.y) + w3 * bflo(q3.y);
            a3 += w0 * bfhi(q0.y) + w1 * bfhi(q1.y) + w2 * bfhi(q2.y) + w3 * bfhi(q3.y);
        }
        for (; r < clen; r += 8) {
            float s0v = inl ? s_loc[r] : sfall[lo + r];
            float e0 = s0v + d; e0 = e0 > 0.f ? e0 : 0.01f * e0;
            float w0 = __expf(e0 - M);
            uint2 q0 = *(const uint2*)&xc2[r][2 * lane];
            den += w0;
            a0 += w0 * bflo(q0.x); a1 += w0 * bfhi(q0.x);
            a2 += w0 * bflo(q0.y); a3 += w0 * bfhi(q0.y);
        }
        // ---- tail rows beyond CROWS: stream from global (L3-hot) ----
        for (int rr = clen + wv; rr < len; rr += 8) {
            float sv = inl ? s_loc[rr] : sfall[lo + rr];
            float e0 = sv + d; e0 = e0 > 0.f ? e0 : 0.01f * e0;
            float w0 = __expf(e0 - M);
            const float4 r0 = *(const float4*)(x + (size_t)(lo + rr) * HDIM + 4 * lane);
            den += w0;
            a0 += w0 * r0.x; a1 += w0 * r0.y; a2 += w0 * r0.z; a3 += w0 * r0.w;
        }
        comb[wv][4 * lane + 0] = a0; comb[wv][4 * lane + 1] = a1;
        comb[wv][4 * lane + 2] = a2; comb[wv][4 * lane + 3] = a3;
        if (lane == 0) dred[wv] = den;
        __syncthreads();
        float dtot = (dred[0] + dred[1]) + (dred[2] + dred[3])
                   + (dred[4] + dred[5]) + (dred[6] + dred[7]);
        float inv = (len > 0) ? 1.0f / dtot : 0.f;
        if (t < HDIM) {
            float s8 = 0.f;
            #pragma unroll
            for (int j = 0; j < 8; ++j) s8 += comb[j][t];
            axv[t] = s8 * inv;
        }
        __syncthreads();

        // ---- h = elu(ax @ W + bias), bf16-pair W, 2-way k-split ----
        {
            float acc = q ? 0.f : bias_gat[tt];
            int k2e = q * 64 + 64;
            for (int k2 = q * 64; k2 < k2e; ++k2) {
                unsigned int w2 = Wpk[(size_t)k2 * HDIM + tt];
                float2 a2 = *(const float2*)&axv[2 * k2];
                acc += a2.x * bflo(w2) + a2.y * bfhi(w2);
            }
            comb[q][tt] = acc;
        }
        __syncthreads();
        if (t < HDIM) {
            float hs = comb[0][t] + comb[1][t];
            hvec[t] = hs > 0.f ? hs : expm1f(hs);
        }
        __syncthreads();

        // ---- GRU matvecs, 2-way k-split, 3 coalesced bf16-pair planes ----
        float gr = 0.f, gz = 0.f, gn = 0.f, hr = 0.f, hz = 0.f, hn = 0.f;
        {
            int k0e = q * 128 + 128;
            for (int k0 = q * 128; k0 < k0e; k0 += 4) {
                float hq[4], oq[4];
                *(float4*)hq = *(const float4*)&hvec[k0];
                *(float4*)oq = *(const float4*)&oprev[k0];
                #pragma unroll
                for (int j = 0; j < 4; ++j) {
                    int kt = (k0 + j) * HDIM + tt;
                    unsigned int u0 = Wgu[kt];
                    unsigned int u1 = Wgu[HDIM * HDIM + kt];
                    unsigned int u2 = Wgu[2 * HDIM * HDIM + kt];
                    gr += hq[j] * bflo(u0);
                    gz += hq[j] * bfhi(u0);
                    gn += hq[j] * bflo(u1);
                    hr += oq[j] * bfhi(u1);
                    hz += oq[j] * bflo(u2);
                    hn += oq[j] * bfhi(u2);
                }
            }
        }
        if (q == 1) {
            comb[0][tt] = gr; comb[1][tt] = gz; comb[2][tt] = gn;
            comb[3][tt] = hr; comb[4][tt] = hz; comb[5][tt] = hn;
        }
        __syncthreads();
        if (q == 0) {
            float gir = gr + comb[0][tt] + b_ih[tt];
            float giz = gz + comb[1][tt] + b_ih[HDIM + tt];
            float gin = gn + comb[2][tt] + b_ih[2 * HDIM + tt];
            float ghr = hr + comb[3][tt] + b_hh[tt];
            float ghz = hz + comb[4][tt] + b_hh[HDIM + tt];
            float ghn = hn + comb[5][tt] + b_hh[2 * HDIM + tt];
            float rg = 1.f / (1.f + __expf(-(gir + ghr)));
            float zg = 1.f / (1.f + __expf(-(giz + ghz)));
            float ng = tanhf(gin + rg * ghn);
            float prev = oprev[tt];
            float h2 = (1.f - zg) * ng + zg * prev;
            float no = h2 / (1.f + __expf(-h2));      // silu
            oprev[tt] = no;
            red[tt] = no * ut;
        }
        __syncthreads();
        for (int st = 128; st > 0; st >>= 1) { if (t < st) red[t] += red[t + st]; __syncthreads(); }
        d = red[0];                                   // d for next timestep
        __syncthreads();
    }

    // ============ final: out2 @ W_lin + b_lin (fp32, 4-way k-split) ============
    {
        int qq = t >> 7, o = t & 127;                 // qq in [0,4)
        float acc = 0.f;
        int ke = qq * 64 + 64;
        #pragma unroll 8
        for (int k = qq * 64; k < ke; ++k)
            acc += oprev[k] * W_lin[(size_t)k * ODIM + o];
        comb[qq][o] = acc;
    }
    __syncthreads();
    if (t < ODIM)
        out[(size_t)b * ODIM + t] = (comb[0][t] + comb[1][t])
                                  + (comb[2][t] + comb[3][t]) + b_lin[t];
}

extern "C" void kernel_launch(void* const* d_in, const int* in_sizes, int n_in,
                              void* d_out, int out_size, void* d_ws, size_t ws_size,
                              hipStream_t stream) {
    const float* x        = (const float*)d_in[0];
    const int*   batch    = (const int*)d_in[1];
    const float* W        = (const float*)d_in[2];
    const float* att_src  = (const float*)d_in[3];
    const float* att_dst  = (const float*)d_in[4];
    const float* bias_gat = (const float*)d_in[5];
    const float* W_ih     = (const float*)d_in[6];
    const float* W_hh     = (const float*)d_in[7];
    const float* b_ih     = (const float*)d_in[8];
    const float* b_hh     = (const float*)d_in[9];
    const float* W_lin    = (const float*)d_in[10];
    const float* b_lin    = (const float*)d_in[11];

    char* ws = (char*)d_ws;
    size_t off = 0;
    auto alloc = [&](size_t bytes) {
        void* p = (void*)(ws + off);
        off += (bytes + 255) & ~(size_t)255;
        return p;
    };
    int*          seg   = (int*)alloc((BGRAPH + 1) * 4);
    float*        vv    = (float*)alloc(HDIM * 4);
    float*        uu    = (float*)alloc(HDIM * 4);
    float*        sfall = (float*)alloc((size_t)N_NODES * 4);
    unsigned int* Wgu   = (unsigned int*)alloc((size_t)3 * HDIM * HDIM * 4);
    unsigned int* Wpk   = (unsigned int*)alloc((size_t)(HDIM / 2) * HDIM * 4);

    hipLaunchKernelGGL(k_prep, dim3(645), dim3(256), 0, stream,
                       W, att_src, att_dst, batch, W_ih, W_hh, vv, uu, seg, Wgu, Wpk);
    hipLaunchKernelGGL(k_fused, dim3(BGRAPH), dim3(512), 0, stream,
                       x, seg, vv, uu, bias_gat, Wgu, Wpk, b_ih, b_hh,
                       W_lin, b_lin, sfall, (float*)d_out);
}

// Round 7
// 458.229 us; speedup vs baseline: 1.7338x; 1.2570x over previous
//
#include <hip/hip_runtime.h>
#include <math.h>

#define N_NODES 200000
#define BGRAPH  1024
#define HDIM    256
#define ODIM    128
#define CROWS   128    // x rows cached per graph in LDS (bf16)
#define SLEN    512    // max segment length with scores in LDS (actual max ~250)

__device__ __forceinline__ unsigned short f2bf(float f) {
    union { float f; unsigned int i; } c; c.f = f;
    unsigned int i = c.i;
    unsigned int r = i + 0x7FFFu + ((i >> 16) & 1u);  // RNE
    return (unsigned short)(r >> 16);
}
// bf16 pair decode: low half = <<16, high half = AND mask
__device__ __forceinline__ float bflo(unsigned int u) {
    union { unsigned int i; float f; } c; c.i = u << 16; return c.f;
}
__device__ __forceinline__ float bfhi(unsigned int u) {
    union { unsigned int i; float f; } c; c.i = u & 0xffff0000u; return c.f;
}

// ---------------------------------------------------------------------------
// k_prep:
//   blocks 0..255   : v[i] = W[i,:].att_src, u[i] = W[i,:].att_dst
//   blocks 256..260 : segment bounds via binary search (batch sorted)
//   blocks 261..516 : pack GRU weights into 3 coalesced bf16-pair planes:
//                     G0[k*256+t]=Wih_r|Wih_z  G1=Wih_n|Whh_r  G2=Whh_z|Whh_n
//   blocks 517..644 : pack W as bf16 pairs: Wpk[k2*256+t]=(W[2k2][t],W[2k2+1][t])
__global__ __launch_bounds__(256) void k_prep(const float* __restrict__ W,
        const float* __restrict__ att_src, const float* __restrict__ att_dst,
        const int* __restrict__ batch, const float* __restrict__ W_ih,
        const float* __restrict__ W_hh, float* __restrict__ v,
        float* __restrict__ u, int* __restrict__ seg,
        unsigned int* __restrict__ Wgu, unsigned int* __restrict__ Wpk) {
    int t = threadIdx.x;
    if (blockIdx.x < 256) {
        int i = blockIdx.x;
        float w = W[(size_t)i * HDIM + t];
        __shared__ float r1[256], r2[256];
        r1[t] = w * att_src[t];
        r2[t] = w * att_dst[t];
        __syncthreads();
        for (int st = 128; st > 0; st >>= 1) {
            if (t < st) { r1[t] += r1[t + st]; r2[t] += r2[t + st]; }
            __syncthreads();
        }
        if (t == 0) { v[i] = r1[0]; u[i] = r2[0]; }
    } else if (blockIdx.x < 261) {
        int b = (blockIdx.x - 256) * 256 + t;
        if (b > BGRAPH) return;
        if (b == BGRAPH) { seg[b] = N_NODES; return; }
        int lo = 0, hi = N_NODES;
        while (lo < hi) { int mid = (lo + hi) >> 1; if (batch[mid] < b) lo = mid + 1; else hi = mid; }
        seg[b] = lo;
    } else if (blockIdx.x < 517) {
        int k = blockIdx.x - 261;            // 0..255
        unsigned int a0 = f2bf(W_ih[(size_t)(0 * HDIM + t) * HDIM + k]);
        unsigned int a1 = f2bf(W_ih[(size_t)(1 * HDIM + t) * HDIM + k]);
        unsigned int a2 = f2bf(W_ih[(size_t)(2 * HDIM + t) * HDIM + k]);
        unsigned int a3 = f2bf(W_hh[(size_t)(0 * HDIM + t) * HDIM + k]);
        unsigned int a4 = f2bf(W_hh[(size_t)(1 * HDIM + t) * HDIM + k]);
        unsigned int a5 = f2bf(W_hh[(size_t)(2 * HDIM + t) * HDIM + k]);
        int kt = k * HDIM + t;
        Wgu[kt]                   = a0 | (a1 << 16);
        Wgu[HDIM * HDIM + kt]     = a2 | (a3 << 16);
        Wgu[2 * HDIM * HDIM + kt] = a4 | (a5 << 16);
    } else {
        int k2 = blockIdx.x - 517;           // 0..127
        unsigned int lo16 = f2bf(W[(size_t)(2 * k2) * HDIM + t]);
        unsigned int hi16 = f2bf(W[(size_t)(2 * k2 + 1) * HDIM + t]);
        Wpk[(size_t)k2 * HDIM + t] = lo16 | (hi16 << 16);
    }
}

// ---------------------------------------------------------------------------
// k_fused: one graph per 512-thread block (8 waves), grid 1024.
// Pass 1 streams x from HBM and CACHES the first CROWS=128 rows in LDS as
// bf16 (64 KB) -> both aggregation sweeps read mostly LDS instead of L3.
// LDS ~80 KB -> 2 blocks/CU (16 waves = 4 waves/SIMD -> needs <=128 VGPR).
// __launch_bounds__(512,2): empirical VGPR cap = 256/arg (R4 (512,8)->32,
// R6 (512,4)->64, both spilled hundreds of MB). (512,2) -> 128-VGPR cap,
// kernel demand ~100 -> no spill, occupancy LDS-limited at 2 blocks/CU.
__global__ __launch_bounds__(512, 2) void k_fused(const float* __restrict__ x,
        const int* __restrict__ seg, const float* __restrict__ v,
        const float* __restrict__ u, const float* __restrict__ bias_gat,
        const unsigned int* __restrict__ Wgu, const unsigned int* __restrict__ Wpk,
        const float* __restrict__ b_ih, const float* __restrict__ b_hh,
        const float* __restrict__ W_lin, const float* __restrict__ b_lin,
        float* __restrict__ sfall, float* __restrict__ out) {
    int b = blockIdx.x;
    int lo = seg[b], hi = seg[b + 1];
    int len = hi - lo;
    int t = threadIdx.x, wv = t >> 6, lane = t & 63;

    __shared__ unsigned int xc2[CROWS][HDIM / 2];  // 64 KB bf16 row cache
    __shared__ float s_loc[SLEN];      // per-row scores
    __shared__ float comb[8][HDIM];    // cross-wave reduce scratch (reused)
    __shared__ float red[HDIM];        // scalar reduce scratch
    __shared__ float axv[HDIM];        // weighted-average vector
    __shared__ float hvec[HDIM];       // GAT output h (GRU input)
    __shared__ float oprev[HDIM];      // running out (pool -> out1 -> out2)
    __shared__ float sred[8], dred[8];

    bool inl = len <= SLEN;
    int clen = len < CROWS ? len : CROWS;
    float ut = u[t & 255];

    // ================= pass 1: pool + s + smax + bf16 cache =================
    float v0 = v[4 * lane + 0], v1 = v[4 * lane + 1];
    float v2 = v[4 * lane + 2], v3 = v[4 * lane + 3];
    float p0 = 0.f, p1 = 0.f, p2 = 0.f, p3 = 0.f;
    float sm = -3.402823466e38f;
    int i = lo + wv;
    for (; i + 8 < hi; i += 16) {
        const float4 r0 = *(const float4*)(x + (size_t)i * HDIM + 4 * lane);
        const float4 r1 = *(const float4*)(x + (size_t)(i + 8) * HDIM + 4 * lane);
        p0 += r0.x + r1.x; p1 += r0.y + r1.y; p2 += r0.z + r1.z; p3 += r0.w + r1.w;
        float pa = r0.x * v0 + r0.y * v1 + r0.z * v2 + r0.w * v3;
        float pb = r1.x * v0 + r1.y * v1 + r1.z * v2 + r1.w * v3;
        #pragma unroll
        for (int off = 32; off > 0; off >>= 1) {
            pa += __shfl_down(pa, off, 64);
            pb += __shfl_down(pb, off, 64);
        }
        int ra = i - lo, rb = ra + 8;
        if (ra < CROWS) {   // wave-uniform branch
            unsigned int c0 = (__float_as_uint(r0.y) & 0xffff0000u) | (__float_as_uint(r0.x) >> 16);
            unsigned int c1 = (__float_as_uint(r0.w) & 0xffff0000u) | (__float_as_uint(r0.z) >> 16);
            *(uint2*)&xc2[ra][2 * lane] = make_uint2(c0, c1);
        }
        if (rb < CROWS) {
            unsigned int c0 = (__float_as_uint(r1.y) & 0xffff0000u) | (__float_as_uint(r1.x) >> 16);
            unsigned int c1 = (__float_as_uint(r1.w) & 0xffff0000u) | (__float_as_uint(r1.z) >> 16);
            *(uint2*)&xc2[rb][2 * lane] = make_uint2(c0, c1);
        }
        if (lane == 0) {
            if (inl) { s_loc[ra] = pa; s_loc[rb] = pb; }
            else     { sfall[i] = pa; sfall[i + 8] = pb; }
            sm = fmaxf(sm, fmaxf(pa, pb));
        }
    }
    for (; i < hi; i += 8) {
        const float4 r0 = *(const float4*)(x + (size_t)i * HDIM + 4 * lane);
        p0 += r0.x; p1 += r0.y; p2 += r0.z; p3 += r0.w;
        float pa = r0.x * v0 + r0.y * v1 + r0.z * v2 + r0.w * v3;
        #pragma unroll
        for (int off = 32; off > 0; off >>= 1) pa += __shfl_down(pa, off, 64);
        int ra = i - lo;
        if (ra < CROWS) {
            unsigned int c0 = (__float_as_uint(r0.y) & 0xffff0000u) | (__float_as_uint(r0.x) >> 16);
            unsigned int c1 = (__float_as_uint(r0.w) & 0xffff0000u) | (__float_as_uint(r0.z) >> 16);
            *(uint2*)&xc2[ra][2 * lane] = make_uint2(c0, c1);
        }
        if (lane == 0) {
            if (inl) s_loc[ra] = pa; else sfall[i] = pa;
            sm = fmaxf(sm, pa);
        }
    }
    comb[wv][4 * lane + 0] = p0; comb[wv][4 * lane + 1] = p1;
    comb[wv][4 * lane + 2] = p2; comb[wv][4 * lane + 3] = p3;
    if (lane == 0) sred[wv] = sm;
    __syncthreads();
    if (t < HDIM) {
        float st0 = 0.f;
        #pragma unroll
        for (int j = 0; j < 8; ++j) st0 += comb[j][t];
        oprev[t] = st0;                              // out0 = pooled sum
        red[t] = st0 * ut;
    }
    float smx = fmaxf(fmaxf(fmaxf(sred[0], sred[1]), fmaxf(sred[2], sred[3])),
                      fmaxf(fmaxf(sred[4], sred[5]), fmaxf(sred[6], sred[7])));
    __syncthreads();
    for (int st = 128; st > 0; st >>= 1) { if (t < st) red[t] += red[t + st]; __syncthreads(); }
    float d = red[0];                                // d1 = out0 . u
    __syncthreads();

    int q = t >> 8, tt = t & 255;                    // 2-way k-split roles

    // ================= T = 2 recurrence, all block-local =================
    for (int step = 0; step < 2; ++step) {
        float M = smx + d;
        M = M > 0.f ? M : 0.01f * M;                 // max of leakyrelu(s_i+d)

        // ---- weighted aggregation: cached rows from LDS (bf16), 2-row unroll ----
        float a0 = 0.f, a1 = 0.f, a2 = 0.f, a3 = 0.f, den = 0.f;
        int r = wv;
        for (; r + 8 < clen; r += 16) {
            float s0v = inl ? s_loc[r]     : sfall[lo + r];
            float s1v = inl ? s_loc[r + 8] : sfall[lo + r + 8];
            float e0 = s0v + d; e0 = e0 > 0.f ? e0 : 0.01f * e0;
            float e1 = s1v + d; e1 = e1 > 0.f ? e1 : 0.01f * e1;
            float w0 = __expf(e0 - M), w1 = __expf(e1 - M);
            uint2 q0 = *(const uint2*)&xc2[r][2 * lane];
            uint2 q1 = *(const uint2*)&xc2[r + 8][2 * lane];
            den += w0 + w1;
            a0 += w0 * bflo(q0.x) + w1 * bflo(q1.x);
            a1 += w0 * bfhi(q0.x) + w1 * bfhi(q1.x);
            a2 += w0 * bflo(q0.y) + w1 * bflo(q1.y);
            a3 += w0 * bfhi(q0.y) + w1 * bfhi(q1.y);
        }
        for (; r < clen; r += 8) {
            float s0v = inl ? s_loc[r] : sfall[lo + r];
            float e0 = s0v + d; e0 = e0 > 0.f ? e0 : 0.01f * e0;
            float w0 = __expf(e0 - M);
            uint2 q0 = *(const uint2*)&xc2[r][2 * lane];
            den += w0;
            a0 += w0 * bflo(q0.x); a1 += w0 * bfhi(q0.x);
            a2 += w0 * bflo(q0.y); a3 += w0 * bfhi(q0.y);
        }
        // ---- tail rows beyond CROWS: stream from global (L3-hot) ----
        for (int rr = clen + wv; rr < len; rr += 8) {
            float sv = inl ? s_loc[rr] : sfall[lo + rr];
            float e0 = sv + d; e0 = e0 > 0.f ? e0 : 0.01f * e0;
            float w0 = __expf(e0 - M);
            const float4 r0 = *(const float4*)(x + (size_t)(lo + rr) * HDIM + 4 * lane);
            den += w0;
            a0 += w0 * r0.x; a1 += w0 * r0.y; a2 += w0 * r0.z; a3 += w0 * r0.w;
        }
        comb[wv][4 * lane + 0] = a0; comb[wv][4 * lane + 1] = a1;
        comb[wv][4 * lane + 2] = a2; comb[wv][4 * lane + 3] = a3;
        if (lane == 0) dred[wv] = den;
        __syncthreads();
        float dtot = (dred[0] + dred[1]) + (dred[2] + dred[3])
                   + (dred[4] + dred[5]) + (dred[6] + dred[7]);
        float inv = (len > 0) ? 1.0f / dtot : 0.f;
        if (t < HDIM) {
            float s8 = 0.f;
            #pragma unroll
            for (int j = 0; j < 8; ++j) s8 += comb[j][t];
            axv[t] = s8 * inv;
        }
        __syncthreads();

        // ---- h = elu(ax @ W + bias), bf16-pair W, 2-way k-split ----
        {
            float acc = q ? 0.f : bias_gat[tt];
            int k2e = q * 64 + 64;
            for (int k2 = q * 64; k2 < k2e; ++k2) {
                unsigned int w2 = Wpk[(size_t)k2 * HDIM + tt];
                float2 a2 = *(const float2*)&axv[2 * k2];
                acc += a2.x * bflo(w2) + a2.y * bfhi(w2);
            }
            comb[q][tt] = acc;
        }
        __syncthreads();
        if (t < HDIM) {
            float hs = comb[0][t] + comb[1][t];
            hvec[t] = hs > 0.f ? hs : expm1f(hs);
        }
        __syncthreads();

        // ---- GRU matvecs, 2-way k-split, 3 coalesced bf16-pair planes ----
        float gr = 0.f, gz = 0.f, gn = 0.f, hr = 0.f, hz = 0.f, hn = 0.f;
        {
            int k0e = q * 128 + 128;
            for (int k0 = q * 128; k0 < k0e; k0 += 4) {
                float hq[4], oq[4];
                *(float4*)hq = *(const float4*)&hvec[k0];
                *(float4*)oq = *(const float4*)&oprev[k0];
                #pragma unroll
                for (int j = 0; j < 4; ++j) {
                    int kt = (k0 + j) * HDIM + tt;
                    unsigned int u0 = Wgu[kt];
                    unsigned int u1 = Wgu[HDIM * HDIM + kt];
                    unsigned int u2 = Wgu[2 * HDIM * HDIM + kt];
                    gr += hq[j] * bflo(u0);
                    gz += hq[j] * bfhi(u0);
                    gn += hq[j] * bflo(u1);
                    hr += oq[j] * bfhi(u1);
                    hz += oq[j] * bflo(u2);
                    hn += oq[j] * bfhi(u2);
                }
            }
        }
        if (q == 1) {
            comb[0][tt] = gr; comb[1][tt] = gz; comb[2][tt] = gn;
            comb[3][tt] = hr; comb[4][tt] = hz; comb[5][tt] = hn;
        }
        __syncthreads();
        if (q == 0) {
            float gir = gr + comb[0][tt] + b_ih[tt];
            float giz = gz + comb[1][tt] + b_ih[HDIM + tt];
            float gin = gn + comb[2][tt] + b_ih[2 * HDIM + tt];
            float ghr = hr + comb[3][tt] + b_hh[tt];
            float ghz = hz + comb[4][tt] + b_hh[HDIM + tt];
            float ghn = hn + comb[5][tt] + b_hh[2 * HDIM + tt];
            float rg = 1.f / (1.f + __expf(-(gir + ghr)));
            float zg = 1.f / (1.f + __expf(-(giz + ghz)));
            float ng = tanhf(gin + rg * ghn);
            float prev = oprev[tt];
            float h2 = (1.f - zg) * ng + zg * prev;
            float no = h2 / (1.f + __expf(-h2));      // silu
            oprev[tt] = no;
            red[tt] = no * ut;
        }
        __syncthreads();
        for (int st = 128; st > 0; st >>= 1) { if (t < st) red[t] += red[t + st]; __syncthreads(); }
        d = red[0];                                   // d for next timestep
        __syncthreads();
    }

    // ============ final: out2 @ W_lin + b_lin (fp32, 4-way k-split) ============
    {
        int qq = t >> 7, o = t & 127;                 // qq in [0,4)
        float acc = 0.f;
        int ke = qq * 64 + 64;
        #pragma unroll 8
        for (int k = qq * 64; k < ke; ++k)
            acc += oprev[k] * W_lin[(size_t)k * ODIM + o];
        comb[qq][o] = acc;
    }
    __syncthreads();
    if (t < ODIM)
        out[(size_t)b * ODIM + t] = (comb[0][t] + comb[1][t])
                                  + (comb[2][t] + comb[3][t]) + b_lin[t];
}

extern "C" void kernel_launch(void* const* d_in, const int* in_sizes, int n_in,
                              void* d_out, int out_size, void* d_ws, size_t ws_size,
                              hipStream_t stream) {
    const float* x        = (const float*)d_in[0];
    const int*   batch    = (const int*)d_in[1];
    const float* W        = (const float*)d_in[2];
    const float* att_src  = (const float*)d_in[3];
    const float* att_dst  = (const float*)d_in[4];
    const float* bias_gat = (const float*)d_in[5];
    const float* W_ih     = (const float*)d_in[6];
    const float* W_hh     = (const float*)d_in[7];
    const float* b_ih     = (const float*)d_in[8];
    const float* b_hh     = (const float*)d_in[9];
    const float* W_lin    = (const float*)d_in[10];
    const float* b_lin    = (const float*)d_in[11];

    char* ws = (char*)d_ws;
    size_t off = 0;
    auto alloc = [&](size_t bytes) {
        void* p = (void*)(ws + off);
        off += (bytes + 255) & ~(size_t)255;
        return p;
    };
    int*          seg   = (int*)alloc((BGRAPH + 1) * 4);
    float*        vv    = (float*)alloc(HDIM * 4);
    float*        uu    = (float*)alloc(HDIM * 4);
    float*        sfall = (float*)alloc((size_t)N_NODES * 4);
    unsigned int* Wgu   = (unsigned int*)alloc((size_t)3 * HDIM * HDIM * 4);
    unsigned int* Wpk   = (unsigned int*)alloc((size_t)(HDIM / 2) * HDIM * 4);

    hipLaunchKernelGGL(k_prep, dim3(645), dim3(256), 0, stream,
                       W, att_src, att_dst, batch, W_ih, W_hh, vv, uu, seg, Wgu, Wpk);
    hipLaunchKernelGGL(k_fused, dim3(BGRAPH), dim3(512), 0, stream,
                       x, seg, vv, uu, bias_gat, Wgu, Wpk, b_ih, b_hh,
                       W_lin, b_lin, sfall, (float*)d_out);
}